// Round 17
// baseline (457.016 us; speedup 1.0000x reference)
//
#include <hip/hip_runtime.h>
#include <stdint.h>

#define NLAYER 2
#define NHEAD 12
#define D 768
#define BB 4
#define LL 1024
#define M (BB*LL)
#define DK 64
#define CSC 0.1803368801111204f   /* 0.125 * log2(e), folded into Q at projection */

typedef unsigned short u16;
typedef unsigned int u32;
typedef unsigned long long u64;
typedef __attribute__((ext_vector_type(8))) __bf16 bf16x8;
typedef __attribute__((ext_vector_type(4))) float f32x4;

__device__ __forceinline__ u16 f2b(float f) {
  u32 u = __float_as_uint(f);
  u += 0x7fffu + ((u >> 16) & 1u);
  return (u16)(u >> 16);
}
__device__ __forceinline__ float b2f(u16 h) {
  return __uint_as_float(((u32)h) << 16);
}
__device__ __forceinline__ f32x4 mfma16(bf16x8 a, bf16x8 b, f32x4 c) {
  return __builtin_amdgcn_mfma_f32_16x16x32_bf16(a, b, c, 0, 0, 0);
}
// async global->LDS, 16B per lane; lds base must be wave-uniform (linear dest: base + lane*16)
__device__ __forceinline__ void gl_lds16(const u16* g, u16* l) {
  __builtin_amdgcn_global_load_lds((const __attribute__((address_space(1))) void*)(g),
                                   (__attribute__((address_space(3))) void*)(l), 16, 0, 0);
}

// ---------------- prep ----------------
__global__ void cast_f32_bf16(const float* __restrict__ src, u16* __restrict__ dst, int n) {
  int i = (blockIdx.x * 256 + threadIdx.x) * 4;
  if (i + 3 < n) {
    float4 v = *(const float4*)(src + i);
    dst[i+0] = f2b(v.x); dst[i+1] = f2b(v.y); dst[i+2] = f2b(v.z); dst[i+3] = f2b(v.w);
  }
}

// wtr[z][n][k] = W[z as (layer,mat,stream)][k][n], bf16
__global__ void wtrans(const float* __restrict__ Wq, const float* __restrict__ Wk,
                       const float* __restrict__ Wv, const float* __restrict__ Wf,
                       u16* __restrict__ wtr) {
  int z = blockIdx.z;
  int layer = z >> 4, mat = (z >> 2) & 3, s = z & 3;
  const float* src = (mat==0?Wq:mat==1?Wk:mat==2?Wv:Wf) + (size_t)(layer*4 + s)*D*D;
  u16* dst = wtr + (size_t)z*D*D;
  __shared__ float tile[32][33];
  int x0 = blockIdx.x*32, y0 = blockIdx.y*32;
  int tx = threadIdx.x & 31, ty = threadIdx.x >> 5;
  #pragma unroll
  for (int i=0;i<4;++i) tile[ty + i*8][tx] = src[(size_t)(y0 + ty + i*8)*D + x0 + tx];
  __syncthreads();
  #pragma unroll
  for (int i=0;i<4;++i) dst[(size_t)(x0 + ty + i*8)*D + y0 + tx] = f2b(tile[tx][ty + i*8]);
}

// pack adjacency ints -> bit masks: mb[s][b][q][w] (u64 words, w = L/64)
__global__ __launch_bounds__(256) void pack_adj(const int* __restrict__ a0, const int* __restrict__ a1,
                                                const int* __restrict__ a2, const int* __restrict__ a3,
                                                u64* __restrict__ mb) {
  const int s = blockIdx.y;
  const int* __restrict__ src = s==0?a0:s==1?a1:s==2?a2:a3;
  u64* dst = mb + (size_t)s * (BB*LL*LL/64);
  const int lane = threadIdx.x & 63;
  const int w0 = blockIdx.x*4 + (threadIdx.x>>6);
  const int wstep = gridDim.x*4;
  for (int w = w0; w < BB*LL*LL/64; w += wstep) {
    int v = src[(size_t)w*64 + lane];
    u64 m = __ballot(v != 0);
    if (lane == 0) dst[w] = m;
  }
}

// ---------------- GEMM: 2-phase pipelined, 8 waves x 64x32 wave-tile, low-reg ----------------
// C[M][768] = A[M][768] @ W^T-stored.  BK=32, double-buffered LDS (32 KB), ONE barrier per
// K-step: STAGE(t+1) issued BEFORE compute(t); the barrier's implicit vmcnt(0) drains loads
// that had the whole MFMA phase in flight. Race-free: buf[(t+1)&1] was last read at t-1,
// fenced by t-1's barrier. Plain HIP only (no asm waitcnts - R8's failure mode).
// cmode==0: C row-major.  cmode==2: row-major scaled by CSC (Q).  cmode==1: V^T layout
// [(b*12+h)*64+d][1024] with k-axis permuted per 64-block to match swapped-QK^T P order:
// k (= l&63) -> p = (r>>1)<<5 | lg<<3 | c<<1 | (r&1), where c=k>>4, lg=(k>>2)&3, r=k&3.
__device__ __forceinline__ void gemm128(const u16* __restrict__ A, const u16* __restrict__ W,
                                        u16* __restrict__ C, int cmode,
                                        int m0, int n0) {
  __shared__ __align__(16) u16 As[2][128*32];   // [buf][row*32+col]
  __shared__ __align__(16) u16 Bs[2][128*32];
  const int t = threadIdx.x;                    // 0..511, 8 waves
  const int wave = t >> 6, lane = t & 63, lg = lane >> 4, lr = lane & 15;
  const int wr = wave >> 2, wc = wave & 3;      // wave tile: rows wr*64+, cols wc*32+
  f32x4 acc[4][2] = {};
  // staging: wave w covers rows [16w,16w+16); lane -> row 16w+(lane>>2), col (lane&3)*8
  const int srow = wave*16 + (lane >> 2);
  const int scol = (lane & 3) << 3;
  const u16* ga0 = A + (size_t)(m0 + srow)*D + scol;
  const u16* gb0 = W + (size_t)(n0 + srow)*D + scol;
  const int l0 = (wave*16)*32;                  // wave-uniform LDS base (u16 idx)

  // prologue: stage tile 0 into buf 0
  gl_lds16(ga0, &As[0][l0]);
  gl_lds16(gb0, &Bs[0][l0]);
  __syncthreads();                              // buf0 resident

  #pragma unroll 2
  for (int tt = 0; tt < 24; ++tt) {             // 24 = D/32 K-steps
    const int cur = tt & 1;
    if (tt < 23) {                              // issue next tile BEFORE compute (overlap)
      const int kk = tt*32 + 32;
      gl_lds16(ga0 + kk, &As[cur^1][l0]);
      gl_lds16(gb0 + kk, &Bs[cur^1][l0]);
    }
    bf16x8 af[4], bfr[2];
    #pragma unroll
    for (int mi=0;mi<4;++mi) af[mi] = *(const bf16x8*)(&As[cur][(wr*64 + mi*16 + lr)*32 + lg*8]);
    #pragma unroll
    for (int ni=0;ni<2;++ni) bfr[ni] = *(const bf16x8*)(&Bs[cur][(wc*32 + ni*16 + lr)*32 + lg*8]);
    #pragma unroll
    for (int mi=0;mi<4;++mi)
      #pragma unroll
      for (int ni=0;ni<2;++ni)
        acc[mi][ni] = mfma16(af[mi], bfr[ni], acc[mi][ni]);
    __syncthreads();                            // drains this step's stage + all buf reads
  }

  if (cmode != 1) {
    const float scl = (cmode == 2) ? CSC : 1.0f;
    #pragma unroll
    for (int mi=0;mi<4;++mi)
      #pragma unroll
      for (int ni=0;ni<2;++ni) {
        int col = n0 + wc*32 + ni*16 + lr;
        #pragma unroll
        for (int r=0;r<4;++r) {
          int row = m0 + wr*64 + mi*16 + lg*4 + r;
          C[(size_t)row*D + col] = f2b(acc[mi][ni][r] * scl);
        }
      }
  } else {
    #pragma unroll
    for (int mi=0;mi<4;++mi)
      #pragma unroll
      for (int ni=0;ni<2;++ni) {
        int col = n0 + wc*32 + ni*16 + lr;
        int h = col >> 6, d = col & 63;
        #pragma unroll
        for (int r=0;r<4;++r) {
          int row = m0 + wr*64 + mi*16 + lg*4 + r;   // row&63 = mi*16 + lg*4 + r
          int p = ((r >> 1) << 5) | (lg << 3) | (mi << 1) | (r & 1);
          int lperm = (row & ~63) | p;
          int b = row >> 10, l = lperm & 1023;
          C[(((size_t)((b*NHEAD + h)<<6) + d) << 10) + l] = f2b(acc[mi][ni][r]);
        }
      }
  }
}

__global__ __launch_bounds__(512) void qkv_gemm(const u16* __restrict__ hA, const u16* __restrict__ hB,
                        const u16* __restrict__ wtr,
                        u16* __restrict__ Qb, u16* __restrict__ Kb, u16* __restrict__ Vtb, int layer) {
  // XCD-chunked swizzle, y-fastest: nwg=2304, 288/XCD; logical -> (z, x, y)
  int bid = blockIdx.x + 32*(blockIdx.y + 6*blockIdx.z);
  int logical = (bid & 7)*288 + (bid >> 3);
  int z = logical / 192, rem = logical % 192;
  int x = rem / 6, y = rem % 6;
  int s = z / 3, which = z % 3;
  const u16* X;
  if (which == 0) X = (s==0||s==3) ? hA : hB;   // xq
  else            X = (s==0||s==2) ? hA : hB;   // xk/xv
  const u16* W = wtr + (size_t)((layer*4 + which)*4 + s)*D*D;
  u16* Cb = (which==0 ? Qb : which==1 ? Kb : Vtb) + (size_t)s*M*D;
  gemm128(X, W, Cb, which == 2 ? 1 : (which == 0 ? 2 : 0), x*128, y*128);
}

__global__ __launch_bounds__(512) void oproj_gemm(const u16* __restrict__ Ob, const u16* __restrict__ wtr,
                          u16* __restrict__ OPb, int layer) {
  // nwg=768, 96/XCD
  int bid = blockIdx.x + 32*(blockIdx.y + 6*blockIdx.z);
  int logical = (bid & 7)*96 + (bid >> 3);
  int s = logical / 192, rem = logical % 192;
  int x = rem / 6, y = rem % 6;
  const u16* W = wtr + (size_t)((layer*4 + 3)*4 + s)*D*D;
  gemm128(Ob + (size_t)s*M*D, W, OPb + (size_t)s*M*D, 0, x*128, y*128);
}

// ---------------- fused masked-softmax attention (QBLK=128, 8 waves, swapped QK^T) ----------------
// R14 structure verbatim (measured best: 82us): LDS-staged K/V (staging IS the coalescer),
// 16 q/wave, ~52 total regs -> high occupancy. Q pre-scaled by CSC at projection.
// Swapped QK^T: sfr = mfma(K,Q) -> lane (lg,lr) holds S[k=kt+16c+lg*4+r][q=q0+lr].
// P stays in-register for PV's A-operand (V's k-axis pre-permuted by the V-GEMM epilogue).
// Fixed-max softmax (scores bounded); row-sum reduced once after the loop.
__global__ __launch_bounds__(512) void attn_kernel(const u16* __restrict__ Qb, const u16* __restrict__ Kb,
                           const u16* __restrict__ Vtb,
                           const u64* __restrict__ mbits,
                           u16* __restrict__ Ob) {
  // XCD-chunked swizzle: 1536 blocks, 8 XCDs -> each XCD owns 192 consecutive
  // logical blocks = 24 whole (b,h,s) K/V panels (L2 reuse).
  int bid = blockIdx.x + 8*(blockIdx.y + 48*blockIdx.z);
  int logical = (bid & 7)*192 + (bid >> 3);
  const int qt = logical & 7;
  const int bhs = logical >> 3;            // 0..191
  const int s = bhs / 48;
  const int bh = bhs % 48;
  const int b = bh / NHEAD, h = bh % NHEAD;

  const int t = threadIdx.x, wave = t >> 6, lane = t & 63, lg = lane >> 4, lr = lane & 15;
  const u16* Q = Qb + (size_t)s*M*D;
  const u16* K = Kb + (size_t)s*M*D;
  u16* O = Ob + (size_t)s*M*D;
  const u64* mbs = mbits + (size_t)s*(BB*LL*LL/64) + (size_t)b*(LL*LL/64);

  __shared__ __align__(16) u16 Ks[64][72];
  __shared__ __align__(16) u16 Vts[64][72];

  const int q0 = qt*128 + wave*16;
  bf16x8 qf0 = *(const bf16x8*)(Q + (size_t)(b*LL + q0 + lr)*D + h*DK + lg*8);
  bf16x8 qf1 = *(const bf16x8*)(Q + (size_t)(b*LL + q0 + lr)*D + h*DK + 32 + lg*8);

  f32x4 of[4] = {};
  float lrow = 0.f;                 // partial row-sum for q=q0+lr; reduced after loop

  // staging: 512 threads, one uint4 each per buffer: row kr, 8 u16 at kc
  const int kr = t >> 3, kc = (t & 7) << 3;
  const u16* Kp  = K + (size_t)(b*LL + kr)*D + h*DK + kc;                     // + kt*D walks tiles
  const u16* Vtp = Vtb + (size_t)s*M*D + ((size_t)(bh*64 + kr) << 10) + kc;   // + kt walks tiles

  uint4 ka = *(const uint4*)(Kp);
  uint4 va = *(const uint4*)(Vtp);
  const int mstride = LL/64;
  u64 mw = mbs[(size_t)(q0 + lr)*mstride];
  u64 mwn;

  for (int kt = 0; kt < LL; kt += 64) {
    __syncthreads();                       // prev tile fully consumed
    *(uint4*)(&Ks[kr][kc])  = ka;
    *(uint4*)(&Vts[kr][kc]) = va;
    if (kt + 64 < LL) {
      ka = *(const uint4*)(Kp + (size_t)(kt+64)*D);
      va = *(const uint4*)(Vtp + kt + 64);
      mwn = mbs[(size_t)(q0 + lr)*mstride + (kt >> 6) + 1];
    }
    __syncthreads();                       // staging visible

    // ---- QK^T (swapped): lane holds S[k=16c+lg*4+r][q=q0+lr] ----
    f32x4 sfr[4];
    __builtin_amdgcn_s_setprio(1);
    #pragma unroll
    for (int c=0;c<4;++c) {
      bf16x8 kf0 = *(const bf16x8*)(&Ks[c*16+lr][lg*8]);
      bf16x8 kf1 = *(const bf16x8*)(&Ks[c*16+lr][32 + lg*8]);
      f32x4 z = {0.f,0.f,0.f,0.f};
      z = mfma16(kf0, qf0, z);
      z = mfma16(kf1, qf1, z);
      sfr[c] = z;
    }
    __builtin_amdgcn_s_setprio(0);

    // ---- P = mask ? exp2(s) : 0  (scale pre-folded into Q; fixed max) ----
    u32 wlo = (u32)(mw >> (lg*4));        // bit (16c+r) for c in {0,1}
    u32 whi = (u32)(mw >> (lg*4 + 32));   // bit (16(c-2)+r) for c in {2,3}
    float pw[4][4];
    #pragma unroll
    for (int c=0;c<4;++c) {
      u32 wsel = (c < 2) ? wlo : whi;
      int sh = (c & 1) << 4;
      #pragma unroll
      for (int r=0;r<4;++r) {
        float e = __builtin_amdgcn_exp2f(sfr[c][r]);
        e = ((wsel >> (sh + r)) & 1u) ? e : 0.f;
        pw[c][r] = e;
        lrow += e;
      }
    }
    mw = mwn;

    // ---- pack P into PV A-fragments in-register (truncating f32->bf16) ----
    union { u32 u[4]; bf16x8 v; } a0, a1;
    #pragma unroll
    for (int c=0;c<4;++c) {
      a0.u[c] = (__float_as_uint(pw[c][0]) >> 16) | (__float_as_uint(pw[c][1]) & 0xffff0000u);
      a1.u[c] = (__float_as_uint(pw[c][2]) >> 16) | (__float_as_uint(pw[c][3]) & 0xffff0000u);
    }

    // ---- PV: of[ni] holds O[q=q0+lg*4+r][d=ni*16+lr] ----
    __builtin_amdgcn_s_setprio(1);
    #pragma unroll
    for (int ni=0;ni<4;++ni) {
      bf16x8 vf0 = *(const bf16x8*)(&Vts[ni*16+lr][lg*8]);
      bf16x8 vf1 = *(const bf16x8*)(&Vts[ni*16+lr][32 + lg*8]);
      of[ni] = mfma16(a0.v, vf0, of[ni]);
      of[ni] = mfma16(a1.v, vf1, of[ni]);
    }
    __builtin_amdgcn_s_setprio(0);
  }

  // ---- row-sum: reduce across the 4 lg groups (lanes lr, lr+16, lr+32, lr+48) ----
  lrow += __shfl_xor(lrow, 16, 64);
  lrow += __shfl_xor(lrow, 32, 64);

  #pragma unroll
  for (int r=0;r<4;++r) {
    float l = __shfl(lrow, lg*4 + r, 64);   // lrow for q = q0+lg*4+r (lanes 0..15 hold all rows)
    float inv = 1.0f / fmaxf(l, 1e-35f);
    int row = b*LL + q0 + lg*4 + r;
    #pragma unroll
    for (int ni=0;ni<4;++ni)
      O[(size_t)row*D + h*DK + ni*16 + lr] = f2b(of[ni][r] * inv);
  }
}

// ---------------- epilogue: residual + LN x4 + relu-combine; single barrier ----------------
__global__ __launch_bounds__(256) void epilogue(const u16* __restrict__ OPb,
                        u16* __restrict__ hA, u16* __restrict__ hB,
                        const float* __restrict__ lng, const float* __restrict__ lnb,
                        const float* __restrict__ inA, const float* __restrict__ inB,
                        float* __restrict__ outA, float* __restrict__ outB,
                        int layer, int last) {
  const int row = blockIdx.x;
  const int t = threadIdx.x;
  __shared__ float red[4][8];       // [wave][4 sums | 4 sqs]
  float av[3], bv[3];
  #pragma unroll
  for (int j=0;j<3;++j) {
    int c = t + j*256;
    av[j] = b2f(hA[(size_t)row*D + c]);
    bv[j] = b2f(hB[(size_t)row*D + c]);
  }
  float o[4][3]; float sum[4] = {0,0,0,0}, sq[4] = {0,0,0,0};
  #pragma unroll
  for (int s=0;s<4;++s) {
    #pragma unroll
    for (int j=0;j<3;++j) {
      int c = t + j*256;
      float v = b2f(OPb[((size_t)s*M + row)*D + c]) + ((s==0||s==3) ? av[j] : bv[j]);
      o[s][j]=v; sum[s]+=v; sq[s]+=v*v;
    }
  }
  #pragma unroll
  for (int off=32; off>0; off>>=1)
    #pragma unroll
    for (int s=0;s<4;++s) { sum[s] += __shfl_down(sum[s], off, 64); sq[s] += __shfl_down(sq[s], off, 64); }
  int wv = t>>6, ln = t&63;
  if (ln==0) {
    #pragma unroll
    for (int s=0;s<4;++s) { red[wv][s] = sum[s]; red[wv][4+s] = sq[s]; }
  }
  __syncthreads();
  float lnv[4][3];
  #pragma unroll
  for (int s=0;s<4;++s) {
    float sm = red[0][s]+red[1][s]+red[2][s]+red[3][s];
    float sk = red[0][4+s]+red[1][4+s]+red[2][4+s]+red[3][4+s];
    float mu = sm * (1.0f/D);
    float var = sk * (1.0f/D) - mu*mu;
    float rstd = rsqrtf(var + 1e-6f);
    #pragma unroll
    for (int j=0;j<3;++j) {
      int c = t + j*256;
      lnv[s][j] = (o[s][j]-mu)*rstd * lng[(layer*4+s)*D + c] + lnb[(layer*4+s)*D + c];
    }
  }
  #pragma unroll
  for (int j=0;j<3;++j) {
    int c = t + j*256;
    float ha = fmaxf(lnv[0][j]+lnv[3][j], 0.f);
    float hb = fmaxf(lnv[1][j]+lnv[2][j], 0.f);
    hA[(size_t)row*D + c] = f2b(ha);
    hB[(size_t)row*D + c] = f2b(hb);
    if (last) {
      outA[(size_t)row*D + c] = inA[(size_t)row*D + c] + ha;
      outB[(size_t)row*D + c] = inB[(size_t)row*D + c] + hb;
    }
  }
}

extern "C" void kernel_launch(void* const* d_in, const int* in_sizes, int n_in,
                              void* d_out, int out_size, void* d_ws, size_t ws_size,
                              hipStream_t stream) {
  const float* h_a = (const float*)d_in[0];
  const float* h_b = (const float*)d_in[1];
  const int* adjA  = (const int*)d_in[2];
  const int* adjB  = (const int*)d_in[3];
  const int* adjAB = (const int*)d_in[4];
  const int* adjBA = (const int*)d_in[5];
  const float* Wq  = (const float*)d_in[6];
  const float* Wk  = (const float*)d_in[7];
  const float* Wv  = (const float*)d_in[8];
  const float* Wf  = (const float*)d_in[9];
  const float* lng = (const float*)d_in[10];
  const float* lnb = (const float*)d_in[11];
  float* outA = (float*)d_out;
  float* outB = outA + (size_t)M*D;

  char* ws = (char*)d_ws;
  size_t off = 0;
  auto alloc = [&](size_t bytes) { void* p = ws + off; off += (bytes + 255) & ~(size_t)255; return p; };
  u16* wtr = (u16*)alloc((size_t)32*D*D*2);
  u16* hAb = (u16*)alloc((size_t)M*D*2);
  u16* hBb = (u16*)alloc((size_t)M*D*2);
  u16* Qb  = (u16*)alloc((size_t)4*M*D*2);
  u16* Kb  = (u16*)alloc((size_t)4*M*D*2);
  u16* Vtb = (u16*)alloc((size_t)4*M*D*2);   // V^T layout [s][(b*12+h)*64+d][1024], k-permuted per 64
  u16* Ob  = (u16*)alloc((size_t)4*M*D*2);
  u64* mbits = (u64*)alloc((size_t)4*BB*LL*LL/64*8);   // 8.4 MB
  u16* OPb = Qb;  // Q dead after attention; reuse for out-proj result

  int n = M*D;
  cast_f32_bf16<<<dim3(n/4/256), 256, 0, stream>>>(h_a, hAb, n);
  cast_f32_bf16<<<dim3(n/4/256), 256, 0, stream>>>(h_b, hBb, n);
  wtrans<<<dim3(24,24,32), 256, 0, stream>>>(Wq, Wk, Wv, Wf, wtr);
  pack_adj<<<dim3(2048,4), 256, 0, stream>>>(adjA, adjB, adjAB, adjBA, mbits);

  for (int layer = 0; layer < NLAYER; ++layer) {
    qkv_gemm<<<dim3(32,6,12), 512, 0, stream>>>(hAb, hBb, wtr, Qb, Kb, Vtb, layer);
    attn_kernel<<<dim3(8,48,4), 512, 0, stream>>>(Qb, Kb, Vtb, mbits, Ob);
    oproj_gemm<<<dim3(32,6,4), 512, 0, stream>>>(Ob, wtr, OPb, layer);
    epilogue<<<dim3(M), 256, 0, stream>>>(OPb, hAb, hBb, lng, lnb, h_a, h_b, outA, outB,
                                          layer, layer == NLAYER-1 ? 1 : 0);
  }
}

// Round 18
// 429.507 us; speedup vs baseline: 1.0640x; 1.0640x over previous
//
#include <hip/hip_runtime.h>
#include <stdint.h>

#define NLAYER 2
#define NHEAD 12
#define D 768
#define BB 4
#define LL 1024
#define M (BB*LL)
#define DK 64
#define CSC 0.1803368801111204f   /* 0.125 * log2(e), folded into Q at projection */

typedef unsigned short u16;
typedef unsigned int u32;
typedef unsigned long long u64;
typedef __attribute__((ext_vector_type(8))) __bf16 bf16x8;
typedef __attribute__((ext_vector_type(4))) float f32x4;

__device__ __forceinline__ u16 f2b(float f) {
  u32 u = __float_as_uint(f);
  u += 0x7fffu + ((u >> 16) & 1u);
  return (u16)(u >> 16);
}
__device__ __forceinline__ float b2f(u16 h) {
  return __uint_as_float(((u32)h) << 16);
}
__device__ __forceinline__ f32x4 mfma16(bf16x8 a, bf16x8 b, f32x4 c) {
  return __builtin_amdgcn_mfma_f32_16x16x32_bf16(a, b, c, 0, 0, 0);
}
// async global->LDS, 16B per lane; lds base must be wave-uniform (linear dest: base + lane*16)
__device__ __forceinline__ void gl_lds16(const u16* g, u16* l) {
  __builtin_amdgcn_global_load_lds((const __attribute__((address_space(1))) void*)(g),
                                   (__attribute__((address_space(3))) void*)(l), 16, 0, 0);
}

// ---------------- prep ----------------
__global__ void cast_f32_bf16(const float* __restrict__ src, u16* __restrict__ dst, int n) {
  int i = (blockIdx.x * 256 + threadIdx.x) * 4;
  if (i + 3 < n) {
    float4 v = *(const float4*)(src + i);
    dst[i+0] = f2b(v.x); dst[i+1] = f2b(v.y); dst[i+2] = f2b(v.z); dst[i+3] = f2b(v.w);
  }
}

// wtr[z][n][k] = W[z as (layer,mat,stream)][k][n], bf16
__global__ void wtrans(const float* __restrict__ Wq, const float* __restrict__ Wk,
                       const float* __restrict__ Wv, const float* __restrict__ Wf,
                       u16* __restrict__ wtr) {
  int z = blockIdx.z;
  int layer = z >> 4, mat = (z >> 2) & 3, s = z & 3;
  const float* src = (mat==0?Wq:mat==1?Wk:mat==2?Wv:Wf) + (size_t)(layer*4 + s)*D*D;
  u16* dst = wtr + (size_t)z*D*D;
  __shared__ float tile[32][33];
  int x0 = blockIdx.x*32, y0 = blockIdx.y*32;
  int tx = threadIdx.x & 31, ty = threadIdx.x >> 5;
  #pragma unroll
  for (int i=0;i<4;++i) tile[ty + i*8][tx] = src[(size_t)(y0 + ty + i*8)*D + x0 + tx];
  __syncthreads();
  #pragma unroll
  for (int i=0;i<4;++i) dst[(size_t)(x0 + ty + i*8)*D + y0 + tx] = f2b(tile[tx][ty + i*8]);
}

// pack adjacency ints -> bit masks: mb[s][b][q][w] (u64 words, w = L/64)
__global__ __launch_bounds__(256) void pack_adj(const int* __restrict__ a0, const int* __restrict__ a1,
                                                const int* __restrict__ a2, const int* __restrict__ a3,
                                                u64* __restrict__ mb) {
  const int s = blockIdx.y;
  const int* __restrict__ src = s==0?a0:s==1?a1:s==2?a2:a3;
  u64* dst = mb + (size_t)s * (BB*LL*LL/64);
  const int lane = threadIdx.x & 63;
  const int w0 = blockIdx.x*4 + (threadIdx.x>>6);
  const int wstep = gridDim.x*4;
  for (int w = w0; w < BB*LL*LL/64; w += wstep) {
    int v = src[(size_t)w*64 + lane];
    u64 m = __ballot(v != 0);
    if (lane == 0) dst[w] = m;
  }
}

// ---------------- GEMM (8 waves x 64x32 wave-tile; low-reg for occupancy) ----------------
// C[M][768] = A[M][768] @ W^T-stored.  BK=64 staged as two [128][32] half-tiles.
// cmode==0: C row-major [M][768].
// cmode==2: row-major, scaled by CSC (Q projection: folds softmax scale into Q).
// cmode==1: C is V^T layout [(b*12+h)*64+d][1024] with the k-axis PERMUTED within each
//            64-block to match the swapped-QK^T P fragment order:
//            k (= l&63) -> p = (r>>1)<<5 | lg<<3 | c<<1 | (r&1), where c=k>>4, lg=(k>>2)&3, r=k&3.
__device__ __forceinline__ void gemm128(const u16* __restrict__ A, const u16* __restrict__ W,
                                        u16* __restrict__ C, int cmode,
                                        int m0, int n0) {
  __shared__ __align__(16) u16 As[2][128*32];   // [kk-half][row*32+col]
  __shared__ __align__(16) u16 Bs[2][128*32];
  const int t = threadIdx.x;                    // 0..511, 8 waves
  const int wave = t >> 6, lane = t & 63, lg = lane >> 4, lr = lane & 15;
  const int wr = wave >> 2, wc = wave & 3;      // wave tile: rows wr*64+, cols wc*32+
  f32x4 acc[4][2] = {};
  // staging: wave w covers rows [16w,16w+16); lane -> row 16w+(lane>>2), col (lane&3)*8
  const int srow = wave*16 + (lane >> 2);
  const int scol = (lane & 3) << 3;
  const u16* ga0 = A + (size_t)(m0 + srow)*D + scol;
  const u16* gb0 = W + (size_t)(n0 + srow)*D + scol;
  const int l0 = (wave*16)*32;                  // wave-uniform LDS base (u16 idx)

  for (int kk = 0; kk < D; kk += 64) {
    __syncthreads();
    #pragma unroll
    for (int hh=0; hh<2; ++hh) {
      const int ko = kk + hh*32;
      gl_lds16(ga0 + ko, &As[hh][l0]);
      gl_lds16(gb0 + ko, &Bs[hh][l0]);
    }
    __syncthreads();
    #pragma unroll
    for (int hh=0; hh<2; ++hh) {
      bf16x8 af[4], bfr[2];
      #pragma unroll
      for (int mi=0;mi<4;++mi) af[mi] = *(const bf16x8*)(&As[hh][(wr*64 + mi*16 + lr)*32 + lg*8]);
      #pragma unroll
      for (int ni=0;ni<2;++ni) bfr[ni] = *(const bf16x8*)(&Bs[hh][(wc*32 + ni*16 + lr)*32 + lg*8]);
      #pragma unroll
      for (int mi=0;mi<4;++mi)
        #pragma unroll
        for (int ni=0;ni<2;++ni)
          acc[mi][ni] = mfma16(af[mi], bfr[ni], acc[mi][ni]);
    }
  }

  if (cmode != 1) {
    const float scl = (cmode == 2) ? CSC : 1.0f;
    #pragma unroll
    for (int mi=0;mi<4;++mi)
      #pragma unroll
      for (int ni=0;ni<2;++ni) {
        int col = n0 + wc*32 + ni*16 + lr;
        #pragma unroll
        for (int r=0;r<4;++r) {
          int row = m0 + wr*64 + mi*16 + lg*4 + r;
          C[(size_t)row*D + col] = f2b(acc[mi][ni][r] * scl);
        }
      }
  } else {
    #pragma unroll
    for (int mi=0;mi<4;++mi)
      #pragma unroll
      for (int ni=0;ni<2;++ni) {
        int col = n0 + wc*32 + ni*16 + lr;
        int h = col >> 6, d = col & 63;
        #pragma unroll
        for (int r=0;r<4;++r) {
          int row = m0 + wr*64 + mi*16 + lg*4 + r;   // row&63 = mi*16 + lg*4 + r
          int p = ((r >> 1) << 5) | (lg << 3) | (mi << 1) | (r & 1);
          int lperm = (row & ~63) | p;
          int b = row >> 10, l = lperm & 1023;
          C[(((size_t)((b*NHEAD + h)<<6) + d) << 10) + l] = f2b(acc[mi][ni][r]);
        }
      }
  }
}

__global__ __launch_bounds__(512) void qkv_gemm(const u16* __restrict__ hA, const u16* __restrict__ hB,
                        const u16* __restrict__ wtr,
                        u16* __restrict__ Qb, u16* __restrict__ Kb, u16* __restrict__ Vtb, int layer) {
  // XCD-chunked swizzle, y-fastest: nwg=2304, 288/XCD; logical -> (z, x, y)
  int bid = blockIdx.x + 32*(blockIdx.y + 6*blockIdx.z);
  int logical = (bid & 7)*288 + (bid >> 3);
  int z = logical / 192, rem = logical % 192;
  int x = rem / 6, y = rem % 6;
  int s = z / 3, which = z % 3;
  const u16* X;
  if (which == 0) X = (s==0||s==3) ? hA : hB;   // xq
  else            X = (s==0||s==2) ? hA : hB;   // xk/xv
  const u16* W = wtr + (size_t)((layer*4 + which)*4 + s)*D*D;
  u16* Cb = (which==0 ? Qb : which==1 ? Kb : Vtb) + (size_t)s*M*D;
  gemm128(X, W, Cb, which == 2 ? 1 : (which == 0 ? 2 : 0), x*128, y*128);
}

__global__ __launch_bounds__(512) void oproj_gemm(const u16* __restrict__ Ob, const u16* __restrict__ wtr,
                          u16* __restrict__ OPb, int layer) {
  // nwg=768, 96/XCD
  int bid = blockIdx.x + 32*(blockIdx.y + 6*blockIdx.z);
  int logical = (bid & 7)*96 + (bid >> 3);
  int s = logical / 192, rem = logical % 192;
  int x = rem / 6, y = rem % 6;
  const u16* W = wtr + (size_t)((layer*4 + 3)*4 + s)*D*D;
  gemm128(Ob + (size_t)s*M*D, W, OPb + (size_t)s*M*D, 0, x*128, y*128);
}

// ---------------- fused masked-softmax attention (QBLK=128, 8 waves, swapped QK^T) ----------------
// R14 structure verbatim (measured best: 82us): LDS-staged K/V (staging IS the coalescer),
// 16 q/wave, ~52 total regs -> high occupancy. Q pre-scaled by CSC at projection.
// Swapped QK^T: sfr = mfma(K,Q) -> lane (lg,lr) holds S[k=kt+16c+lg*4+r][q=q0+lr].
// P stays in-register for PV's A-operand (V's k-axis pre-permuted by the V-GEMM epilogue).
// Fixed-max softmax (scores bounded); row-sum reduced once after the loop.
__global__ __launch_bounds__(512) void attn_kernel(const u16* __restrict__ Qb, const u16* __restrict__ Kb,
                           const u16* __restrict__ Vtb,
                           const u64* __restrict__ mbits,
                           u16* __restrict__ Ob) {
  // XCD-chunked swizzle: 1536 blocks, 8 XCDs -> each XCD owns 192 consecutive
  // logical blocks = 24 whole (b,h,s) K/V panels (L2 reuse).
  int bid = blockIdx.x + 8*(blockIdx.y + 48*blockIdx.z);
  int logical = (bid & 7)*192 + (bid >> 3);
  const int qt = logical & 7;
  const int bhs = logical >> 3;            // 0..191
  const int s = bhs / 48;
  const int bh = bhs % 48;
  const int b = bh / NHEAD, h = bh % NHEAD;

  const int t = threadIdx.x, wave = t >> 6, lane = t & 63, lg = lane >> 4, lr = lane & 15;
  const u16* Q = Qb + (size_t)s*M*D;
  const u16* K = Kb + (size_t)s*M*D;
  u16* O = Ob + (size_t)s*M*D;
  const u64* mbs = mbits + (size_t)s*(BB*LL*LL/64) + (size_t)b*(LL*LL/64);

  __shared__ __align__(16) u16 Ks[64][72];
  __shared__ __align__(16) u16 Vts[64][72];

  const int q0 = qt*128 + wave*16;
  bf16x8 qf0 = *(const bf16x8*)(Q + (size_t)(b*LL + q0 + lr)*D + h*DK + lg*8);
  bf16x8 qf1 = *(const bf16x8*)(Q + (size_t)(b*LL + q0 + lr)*D + h*DK + 32 + lg*8);

  f32x4 of[4] = {};
  float lrow = 0.f;                 // partial row-sum for q=q0+lr; reduced after loop

  // staging: 512 threads, one uint4 each per buffer: row kr, 8 u16 at kc
  const int kr = t >> 3, kc = (t & 7) << 3;
  const u16* Kp  = K + (size_t)(b*LL + kr)*D + h*DK + kc;                     // + kt*D walks tiles
  const u16* Vtp = Vtb + (size_t)s*M*D + ((size_t)(bh*64 + kr) << 10) + kc;   // + kt walks tiles

  uint4 ka = *(const uint4*)(Kp);
  uint4 va = *(const uint4*)(Vtp);
  const int mstride = LL/64;
  u64 mw = mbs[(size_t)(q0 + lr)*mstride];
  u64 mwn;

  for (int kt = 0; kt < LL; kt += 64) {
    __syncthreads();                       // prev tile fully consumed
    *(uint4*)(&Ks[kr][kc])  = ka;
    *(uint4*)(&Vts[kr][kc]) = va;
    if (kt + 64 < LL) {
      ka = *(const uint4*)(Kp + (size_t)(kt+64)*D);
      va = *(const uint4*)(Vtp + kt + 64);
      mwn = mbs[(size_t)(q0 + lr)*mstride + (kt >> 6) + 1];
    }
    __syncthreads();                       // staging visible

    // ---- QK^T (swapped): lane holds S[k=16c+lg*4+r][q=q0+lr] ----
    f32x4 sfr[4];
    __builtin_amdgcn_s_setprio(1);
    #pragma unroll
    for (int c=0;c<4;++c) {
      bf16x8 kf0 = *(const bf16x8*)(&Ks[c*16+lr][lg*8]);
      bf16x8 kf1 = *(const bf16x8*)(&Ks[c*16+lr][32 + lg*8]);
      f32x4 z = {0.f,0.f,0.f,0.f};
      z = mfma16(kf0, qf0, z);
      z = mfma16(kf1, qf1, z);
      sfr[c] = z;
    }
    __builtin_amdgcn_s_setprio(0);

    // ---- P = mask ? exp2(s) : 0  (scale pre-folded into Q; fixed max) ----
    u32 wlo = (u32)(mw >> (lg*4));        // bit (16c+r) for c in {0,1}
    u32 whi = (u32)(mw >> (lg*4 + 32));   // bit (16(c-2)+r) for c in {2,3}
    float pw[4][4];
    #pragma unroll
    for (int c=0;c<4;++c) {
      u32 wsel = (c < 2) ? wlo : whi;
      int sh = (c & 1) << 4;
      #pragma unroll
      for (int r=0;r<4;++r) {
        float e = __builtin_amdgcn_exp2f(sfr[c][r]);
        e = ((wsel >> (sh + r)) & 1u) ? e : 0.f;
        pw[c][r] = e;
        lrow += e;
      }
    }
    mw = mwn;

    // ---- pack P into PV A-fragments in-register (truncating f32->bf16) ----
    union { u32 u[4]; bf16x8 v; } a0, a1;
    #pragma unroll
    for (int c=0;c<4;++c) {
      a0.u[c] = (__float_as_uint(pw[c][0]) >> 16) | (__float_as_uint(pw[c][1]) & 0xffff0000u);
      a1.u[c] = (__float_as_uint(pw[c][2]) >> 16) | (__float_as_uint(pw[c][3]) & 0xffff0000u);
    }

    // ---- PV: of[ni] holds O[q=q0+lg*4+r][d=ni*16+lr] ----
    __builtin_amdgcn_s_setprio(1);
    #pragma unroll
    for (int ni=0;ni<4;++ni) {
      bf16x8 vf0 = *(const bf16x8*)(&Vts[ni*16+lr][lg*8]);
      bf16x8 vf1 = *(const bf16x8*)(&Vts[ni*16+lr][32 + lg*8]);
      of[ni] = mfma16(a0.v, vf0, of[ni]);
      of[ni] = mfma16(a1.v, vf1, of[ni]);
    }
    __builtin_amdgcn_s_setprio(0);
  }

  // ---- row-sum: reduce across the 4 lg groups (lanes lr, lr+16, lr+32, lr+48) ----
  lrow += __shfl_xor(lrow, 16, 64);
  lrow += __shfl_xor(lrow, 32, 64);

  #pragma unroll
  for (int r=0;r<4;++r) {
    float l = __shfl(lrow, lg*4 + r, 64);   // lrow for q = q0+lg*4+r (lanes 0..15 hold all rows)
    float inv = 1.0f / fmaxf(l, 1e-35f);
    int row = b*LL + q0 + lg*4 + r;
    #pragma unroll
    for (int ni=0;ni<4;++ni)
      O[(size_t)row*D + h*DK + ni*16 + lr] = f2b(of[ni][r] * inv);
  }
}

// ---------------- epilogue: residual + LN x4 + relu-combine; single barrier ----------------
__global__ __launch_bounds__(256) void epilogue(const u16* __restrict__ OPb,
                        u16* __restrict__ hA, u16* __restrict__ hB,
                        const float* __restrict__ lng, const float* __restrict__ lnb,
                        const float* __restrict__ inA, const float* __restrict__ inB,
                        float* __restrict__ outA, float* __restrict__ outB,
                        int layer, int last) {
  const int row = blockIdx.x;
  const int t = threadIdx.x;
  __shared__ float red[4][8];       // [wave][4 sums | 4 sqs]
  float av[3], bv[3];
  #pragma unroll
  for (int j=0;j<3;++j) {
    int c = t + j*256;
    av[j] = b2f(hA[(size_t)row*D + c]);
    bv[j] = b2f(hB[(size_t)row*D + c]);
  }
  float o[4][3]; float sum[4] = {0,0,0,0}, sq[4] = {0,0,0,0};
  #pragma unroll
  for (int s=0;s<4;++s) {
    #pragma unroll
    for (int j=0;j<3;++j) {
      int c = t + j*256;
      float v = b2f(OPb[((size_t)s*M + row)*D + c]) + ((s==0||s==3) ? av[j] : bv[j]);
      o[s][j]=v; sum[s]+=v; sq[s]+=v*v;
    }
  }
  #pragma unroll
  for (int off=32; off>0; off>>=1)
    #pragma unroll
    for (int s=0;s<4;++s) { sum[s] += __shfl_down(sum[s], off, 64); sq[s] += __shfl_down(sq[s], off, 64); }
  int wv = t>>6, ln = t&63;
  if (ln==0) {
    #pragma unroll
    for (int s=0;s<4;++s) { red[wv][s] = sum[s]; red[wv][4+s] = sq[s]; }
  }
  __syncthreads();
  float lnv[4][3];
  #pragma unroll
  for (int s=0;s<4;++s) {
    float sm = red[0][s]+red[1][s]+red[2][s]+red[3][s];
    float sk = red[0][4+s]+red[1][4+s]+red[2][4+s]+red[3][4+s];
    float mu = sm * (1.0f/D);
    float var = sk * (1.0f/D) - mu*mu;
    float rstd = rsqrtf(var + 1e-6f);
    #pragma unroll
    for (int j=0;j<3;++j) {
      int c = t + j*256;
      lnv[s][j] = (o[s][j]-mu)*rstd * lng[(layer*4+s)*D + c] + lnb[(layer*4+s)*D + c];
    }
  }
  #pragma unroll
  for (int j=0;j<3;++j) {
    int c = t + j*256;
    float ha = fmaxf(lnv[0][j]+lnv[3][j], 0.f);
    float hb = fmaxf(lnv[1][j]+lnv[2][j], 0.f);
    hA[(size_t)row*D + c] = f2b(ha);
    hB[(size_t)row*D + c] = f2b(hb);
    if (last) {
      outA[(size_t)row*D + c] = inA[(size_t)row*D + c] + ha;
      outB[(size_t)row*D + c] = inB[(size_t)row*D + c] + hb;
    }
  }
}

extern "C" void kernel_launch(void* const* d_in, const int* in_sizes, int n_in,
                              void* d_out, int out_size, void* d_ws, size_t ws_size,
                              hipStream_t stream) {
  const float* h_a = (const float*)d_in[0];
  const float* h_b = (const float*)d_in[1];
  const int* adjA  = (const int*)d_in[2];
  const int* adjB  = (const int*)d_in[3];
  const int* adjAB = (const int*)d_in[4];
  const int* adjBA = (const int*)d_in[5];
  const float* Wq  = (const float*)d_in[6];
  const float* Wk  = (const float*)d_in[7];
  const float* Wv  = (const float*)d_in[8];
  const float* Wf  = (const float*)d_in[9];
  const float* lng = (const float*)d_in[10];
  const float* lnb = (const float*)d_in[11];
  float* outA = (float*)d_out;
  float* outB = outA + (size_t)M*D;

  char* ws = (char*)d_ws;
  size_t off = 0;
  auto alloc = [&](size_t bytes) { void* p = ws + off; off += (bytes + 255) & ~(size_t)255; return p; };
  u16* wtr = (u16*)alloc((size_t)32*D*D*2);
  u16* hAb = (u16*)alloc((size_t)M*D*2);
  u16* hBb = (u16*)alloc((size_t)M*D*2);
  u16* Qb  = (u16*)alloc((size_t)4*M*D*2);
  u16* Kb  = (u16*)alloc((size_t)4*M*D*2);
  u16* Vtb = (u16*)alloc((size_t)4*M*D*2);   // V^T layout [s][(b*12+h)*64+d][1024], k-permuted per 64
  u16* Ob  = (u16*)alloc((size_t)4*M*D*2);
  u64* mbits = (u64*)alloc((size_t)4*BB*LL*LL/64*8);   // 8.4 MB
  u16* OPb = Qb;  // Q dead after attention; reuse for out-proj result

  int n = M*D;
  cast_f32_bf16<<<dim3(n/4/256), 256, 0, stream>>>(h_a, hAb, n);
  cast_f32_bf16<<<dim3(n/4/256), 256, 0, stream>>>(h_b, hBb, n);
  wtrans<<<dim3(24,24,32), 256, 0, stream>>>(Wq, Wk, Wv, Wf, wtr);
  pack_adj<<<dim3(2048,4), 256, 0, stream>>>(adjA, adjB, adjAB, adjBA, mbits);

  for (int layer = 0; layer < NLAYER; ++layer) {
    qkv_gemm<<<dim3(32,6,12), 512, 0, stream>>>(hAb, hBb, wtr, Qb, Kb, Vtb, layer);
    attn_kernel<<<dim3(8,48,4), 512, 0, stream>>>(Qb, Kb, Vtb, mbits, Ob);
    oproj_gemm<<<dim3(32,6,4), 512, 0, stream>>>(Ob, wtr, OPb, layer);
    epilogue<<<dim3(M), 256, 0, stream>>>(OPb, hAb, hBb, lng, lnb, h_a, h_b, outA, outB,
                                          layer, layer == NLAYER-1 ? 1 : 0);
  }
}